// Round 1
// baseline (6644.904 us; speedup 1.0000x reference)
//
#include <hip/hip_runtime.h>
#include <hip/hip_bf16.h>
#include <stdint.h>

#define TPB 256

// ---------- helpers ----------
__device__ __forceinline__ float bfbits2f(uint32_t lo16) {
  union { uint32_t u; float f; } c; c.u = lo16 << 16; return c.f;
}
__device__ __forceinline__ uint16_t f2bf_rne(float f) {
  union { float f; uint32_t u; } c; c.f = f;
  uint32_t r = 0x7FFFu + ((c.u >> 16) & 1u);
  return (uint16_t)((c.u + r) >> 16);
}
// monotone float -> uint key (for atomicMax) and inverse
__device__ __forceinline__ unsigned fkey(float f) {
  union { float f; unsigned u; } c; c.f = f;
  return (c.u & 0x80000000u) ? ~c.u : (c.u | 0x80000000u);
}

// ---------- conv1: feats[N,32] (no pad row; idx==N -> skip) -> y[N,64] ----------
__global__ __launch_bounds__(TPB) void conv1_kernel(
    const float* __restrict__ feats, const float* __restrict__ W,
    const int* __restrict__ nbr, float* __restrict__ y, int N)
{
  __shared__ float Wk[32 * 64]; // 8 KB
  const int tid = threadIdx.x;
  const long long i = (long long)blockIdx.x * TPB + tid;
  const bool active = (i < (long long)N);

  float acc[64];
#pragma unroll
  for (int c = 0; c < 64; ++c) acc[c] = 0.f;

#pragma unroll 1
  for (int k = 0; k < 27; ++k) {
    __syncthreads(); // protect previous iteration's Wk reads
#pragma unroll
    for (int j = 0; j < 8; ++j)
      Wk[tid + TPB * j] = W[(size_t)k * 2048 + tid + TPB * j];
    __syncthreads();

    const int g = active ? nbr[i * 27 + k] : N;
    if (g < N) {
      float f[32];
      const float4* fr = (const float4*)(feats + (size_t)g * 32);
#pragma unroll
      for (int q = 0; q < 8; ++q) {
        float4 v = fr[q];
        f[q * 4 + 0] = v.x; f[q * 4 + 1] = v.y; f[q * 4 + 2] = v.z; f[q * 4 + 3] = v.w;
      }
#pragma unroll
      for (int ci = 0; ci < 32; ++ci) {
        const float4* wr = (const float4*)(Wk + ci * 64);
        const float fv = f[ci];
#pragma unroll
        for (int j = 0; j < 16; ++j) {
          float4 w = wr[j];
          acc[j * 4 + 0] = fmaf(fv, w.x, acc[j * 4 + 0]);
          acc[j * 4 + 1] = fmaf(fv, w.y, acc[j * 4 + 1]);
          acc[j * 4 + 2] = fmaf(fv, w.z, acc[j * 4 + 2]);
          acc[j * 4 + 3] = fmaf(fv, w.w, acc[j * 4 + 3]);
        }
      }
    }
  }
  if (active) {
    float4* yo = (float4*)(y + (size_t)i * 64);
#pragma unroll
    for (int j = 0; j < 16; ++j) {
      float4 v;
      v.x = acc[j * 4 + 0]; v.y = acc[j * 4 + 1]; v.z = acc[j * 4 + 2]; v.w = acc[j * 4 + 3];
      yo[j] = v;
    }
  }
}

// ---------- conv2: x1[(N+1),64] bf16 (pad row N = zeros) -> y[N,64] ----------
__global__ __launch_bounds__(TPB) void conv2_kernel(
    const uint16_t* __restrict__ x1, const float* __restrict__ W,
    const int* __restrict__ nbr, float* __restrict__ y, int N)
{
  __shared__ float Wk[64 * 64]; // 16 KB
  const int tid = threadIdx.x;
  const long long i = (long long)blockIdx.x * TPB + tid;
  const bool active = (i < (long long)N);

  float acc[64];
#pragma unroll
  for (int c = 0; c < 64; ++c) acc[c] = 0.f;

#pragma unroll 1
  for (int k = 0; k < 27; ++k) {
    __syncthreads();
#pragma unroll
    for (int j = 0; j < 16; ++j)
      Wk[tid + TPB * j] = W[(size_t)k * 4096 + tid + TPB * j];
    __syncthreads();

    const int g = active ? nbr[i * 27 + k] : N; // pad row N exists (zeros)
    float f[64];
    const uint4* fr = (const uint4*)(x1 + (size_t)g * 64);
#pragma unroll
    for (int q = 0; q < 8; ++q) {
      uint4 v = fr[q];
      f[q * 8 + 0] = bfbits2f(v.x & 0xFFFFu); f[q * 8 + 1] = bfbits2f(v.x >> 16);
      f[q * 8 + 2] = bfbits2f(v.y & 0xFFFFu); f[q * 8 + 3] = bfbits2f(v.y >> 16);
      f[q * 8 + 4] = bfbits2f(v.z & 0xFFFFu); f[q * 8 + 5] = bfbits2f(v.z >> 16);
      f[q * 8 + 6] = bfbits2f(v.w & 0xFFFFu); f[q * 8 + 7] = bfbits2f(v.w >> 16);
    }
#pragma unroll
    for (int ci = 0; ci < 64; ++ci) {
      const float4* wr = (const float4*)(Wk + ci * 64);
      const float fv = f[ci];
#pragma unroll
      for (int j = 0; j < 16; ++j) {
        float4 w = wr[j];
        acc[j * 4 + 0] = fmaf(fv, w.x, acc[j * 4 + 0]);
        acc[j * 4 + 1] = fmaf(fv, w.y, acc[j * 4 + 1]);
        acc[j * 4 + 2] = fmaf(fv, w.z, acc[j * 4 + 2]);
        acc[j * 4 + 3] = fmaf(fv, w.w, acc[j * 4 + 3]);
      }
    }
  }
  if (active) {
    float4* yo = (float4*)(y + (size_t)i * 64);
#pragma unroll
    for (int j = 0; j < 16; ++j) {
      float4 v;
      v.x = acc[j * 4 + 0]; v.y = acc[j * 4 + 1]; v.z = acc[j * 4 + 2]; v.w = acc[j * 4 + 3];
      yo[j] = v;
    }
  }
}

// ---------- per-channel sum/sumsq of y[N,64] -> stats[0..63]=sum, [64..127]=sumsq ----------
__global__ __launch_bounds__(TPB) void col_stats_kernel(
    const float* __restrict__ y, float* __restrict__ stats, long long N)
{
  const int c = threadIdx.x & 63;
  const int rg = threadIdx.x >> 6; // 0..3
  float s = 0.f, s2 = 0.f;
  for (long long i = (long long)blockIdx.x * 4 + rg; i < N; i += (long long)gridDim.x * 4) {
    float v = y[i * 64 + c];
    s += v;
    s2 = fmaf(v, v, s2);
  }
  __shared__ float ls[2][TPB];
  ls[0][threadIdx.x] = s; ls[1][threadIdx.x] = s2;
  __syncthreads();
  if (threadIdx.x < 64) {
    float ts = ls[0][c] + ls[0][64 + c] + ls[0][128 + c] + ls[0][192 + c];
    float ts2 = ls[1][c] + ls[1][64 + c] + ls[1][128 + c] + ls[1][192 + c];
    atomicAdd(&stats[c], ts);
    atomicAdd(&stats[64 + c], ts2);
  }
}

// ---------- finalize: stats[128..191]=mean, [192..255]=rstd ----------
__global__ void bn_finalize_kernel(float* stats, float n)
{
  int c = threadIdx.x; // 64 threads
  float mean = stats[c] / n;
  float var = stats[64 + c] / n - mean * mean;
  stats[128 + c] = mean;
  stats[192 + c] = rsqrtf(var + 1e-5f);
}

// ---------- BN + ReLU -> x1 bf16 (rows [0,N) from y; row N = zeros) ----------
__global__ __launch_bounds__(TPB) void bn_relu_bf16_kernel(
    const float* __restrict__ y, const float* __restrict__ stats,
    const float* __restrict__ gamma, const float* __restrict__ beta,
    uint16_t* __restrict__ x1, long long N)
{
  long long e = ((long long)blockIdx.x * TPB + threadIdx.x) * 4;
  if (e >= (N + 1) * 64) return;
  long long row = e >> 6;
  int c = (int)(e & 63);
  ushort4 out;
  if (row < N) {
    float4 v = *(const float4*)(y + e);
    float4 m = *(const float4*)(stats + 128 + c);
    float4 r = *(const float4*)(stats + 192 + c);
    float4 g = *(const float4*)(gamma + c);
    float4 b = *(const float4*)(beta + c);
    float o0 = fmaf((v.x - m.x) * r.x, g.x, b.x);
    float o1 = fmaf((v.y - m.y) * r.y, g.y, b.y);
    float o2 = fmaf((v.z - m.z) * r.z, g.z, b.z);
    float o3 = fmaf((v.w - m.w) * r.w, g.w, b.w);
    o0 = o0 > 0.f ? o0 : 0.f; o1 = o1 > 0.f ? o1 : 0.f;
    o2 = o2 > 0.f ? o2 : 0.f; o3 = o3 > 0.f ? o3 : 0.f;
    out.x = f2bf_rne(o0); out.y = f2bf_rne(o1); out.z = f2bf_rne(o2); out.w = f2bf_rne(o3);
  } else {
    out.x = 0; out.y = 0; out.z = 0; out.w = 0;
  }
  *(ushort4*)(x1 + e) = out;
}

// ---------- BN (no relu) -> d_out x region + segment-max atomics (uint keys) ----------
__global__ __launch_bounds__(TPB) void bn_pool_kernel(
    const float* __restrict__ y, const float* __restrict__ stats,
    const float* __restrict__ gamma, const float* __restrict__ beta,
    const int* __restrict__ pool_ids,
    float* __restrict__ xout, unsigned int* __restrict__ pooled_u, long long N)
{
  long long e = ((long long)blockIdx.x * TPB + threadIdx.x) * 4;
  if (e >= N * 64) return;
  long long row = e >> 6;
  int c = (int)(e & 63);
  float4 v = *(const float4*)(y + e);
  float4 m = *(const float4*)(stats + 128 + c);
  float4 r = *(const float4*)(stats + 192 + c);
  float4 g = *(const float4*)(gamma + c);
  float4 b = *(const float4*)(beta + c);
  float4 o;
  o.x = fmaf((v.x - m.x) * r.x, g.x, b.x);
  o.y = fmaf((v.y - m.y) * r.y, g.y, b.y);
  o.z = fmaf((v.z - m.z) * r.z, g.z, b.z);
  o.w = fmaf((v.w - m.w) * r.w, g.w, b.w);
  *(float4*)(xout + e) = o;
  int pid = pool_ids[row];
  unsigned int* pbase = pooled_u + (size_t)pid * 64 + c;
  atomicMax(pbase + 0, fkey(o.x));
  atomicMax(pbase + 1, fkey(o.y));
  atomicMax(pbase + 2, fkey(o.z));
  atomicMax(pbase + 3, fkey(o.w));
}

// ---------- uint keys -> float, in place ----------
__global__ void pool_finalize_kernel(unsigned int* p, long long n)
{
  long long i = (long long)blockIdx.x * TPB + threadIdx.x;
  if (i < n) {
    unsigned u = p[i];
    p[i] = (u & 0x80000000u) ? (u ^ 0x80000000u) : ~u;
  }
}

extern "C" void kernel_launch(void* const* d_in, const int* in_sizes, int n_in,
                              void* d_out, int out_size, void* d_ws, size_t ws_size,
                              hipStream_t stream)
{
  const float* feats  = (const float*)d_in[0];
  const float* W1     = (const float*)d_in[1];
  const float* gamma1 = (const float*)d_in[2];
  const float* beta1  = (const float*)d_in[3];
  const float* W2     = (const float*)d_in[4];
  const float* gamma2 = (const float*)d_in[5];
  const float* beta2  = (const float*)d_in[6];
  const int* nbr      = (const int*)d_in[7];
  const int* pool_ids = (const int*)d_in[8];

  const long long N = (long long)in_sizes[0] / 32;
  const long long P = (long long)out_size / 64 - N;

  char* ws = (char*)d_ws;
  float* y = (float*)ws;                       // [N*64] f32
  size_t y_bytes = (size_t)N * 64 * 4;
  uint16_t* x1 = (uint16_t*)(ws + y_bytes);    // [(N+1)*64] bf16
  size_t x1_bytes = ((size_t)(N + 1) * 64 * 2 + 255) & ~(size_t)255;
  float* stats = (float*)(ws + y_bytes + x1_bytes); // 512 floats (2 sets)
  float* stats2 = stats + 256;

  float* xout = (float*)d_out;
  unsigned int* pooled_u = (unsigned int*)(xout + (size_t)N * 64);

  hipMemsetAsync(stats, 0, 512 * sizeof(float), stream);
  hipMemsetAsync(pooled_u, 0, (size_t)P * 64 * 4, stream);

  const int convBlocks = (int)((N + TPB - 1) / TPB);
  conv1_kernel<<<convBlocks, TPB, 0, stream>>>(feats, W1, nbr, y, (int)N);
  col_stats_kernel<<<256, TPB, 0, stream>>>(y, stats, N);
  bn_finalize_kernel<<<1, 64, 0, stream>>>(stats, (float)N);

  long long e1 = ((N + 1) * 64) / 4;
  bn_relu_bf16_kernel<<<(int)((e1 + TPB - 1) / TPB), TPB, 0, stream>>>(
      y, stats, gamma1, beta1, x1, N);

  conv2_kernel<<<convBlocks, TPB, 0, stream>>>(x1, W2, nbr, y, (int)N);
  col_stats_kernel<<<256, TPB, 0, stream>>>(y, stats2, N);
  bn_finalize_kernel<<<1, 64, 0, stream>>>(stats2, (float)N);

  long long e2 = (N * 64) / 4;
  bn_pool_kernel<<<(int)((e2 + TPB - 1) / TPB), TPB, 0, stream>>>(
      y, stats2, gamma2, beta2, pool_ids, xout, pooled_u, N);

  long long pe = P * 64;
  pool_finalize_kernel<<<(int)((pe + TPB - 1) / TPB), TPB, 0, stream>>>(pooled_u, pe);
}

// Round 2
// 2734.640 us; speedup vs baseline: 2.4299x; 2.4299x over previous
//
#include <hip/hip_runtime.h>
#include <hip/hip_bf16.h>
#include <stdint.h>

#define TPB 256

typedef __bf16 bf16x8 __attribute__((ext_vector_type(8)));
typedef float f32x4 __attribute__((ext_vector_type(4)));
union U16x8 { uint4 u; bf16x8 b; };

// ---------- helpers ----------
__device__ __forceinline__ float bfbits2f(uint32_t lo16) {
  union { uint32_t u; float f; } c; c.u = lo16 << 16; return c.f;
}
__device__ __forceinline__ uint16_t f2bf_rne(float f) {
  union { float f; uint32_t u; } c; c.f = f;
  uint32_t r = 0x7FFFu + ((c.u >> 16) & 1u);
  return (uint16_t)((c.u + r) >> 16);
}
__device__ __forceinline__ unsigned fkey(float f) {
  union { float f; unsigned u; } c; c.f = f;
  return (c.u & 0x80000000u) ? ~c.u : (c.u | 0x80000000u);
}

// ---------- prep: W -> bf16, transposed to [k][cout][cin] ----------
__global__ __launch_bounds__(TPB) void prep_w_kernel(
    const float* __restrict__ W1, const float* __restrict__ W2,
    uint16_t* __restrict__ w1t, uint16_t* __restrict__ w2t)
{
  int i = blockIdx.x * TPB + threadIdx.x;
  if (i < 27 * 2048) {
    int k = i >> 11, cin = (i >> 6) & 31, cout = i & 63;
    w1t[(k << 11) + (cout << 5) + cin] = f2bf_rne(W1[i]);
  } else {
    int j = i - 27 * 2048;
    if (j < 27 * 4096) {
      int k = j >> 12, cin = (j >> 6) & 63, cout = j & 63;
      w2t[(k << 12) + (cout << 6) + cin] = f2bf_rne(W2[j]);
    }
  }
}

// ---------- prep: feats f32 [N,32] -> bf16 [(N+1),32] with zero pad row ----------
__global__ __launch_bounds__(TPB) void prep_x0_kernel(
    const float* __restrict__ feats, uint16_t* __restrict__ x0, long long N)
{
  long long t = (long long)blockIdx.x * TPB + threadIdx.x;
  if (t >= (N + 1) * 4) return;
  long long e = t * 8;
  uint4 o;
  if (e < N * 32) {
    float4 a = *(const float4*)(feats + e);
    float4 b = *(const float4*)(feats + e + 4);
    o.x = (uint32_t)f2bf_rne(a.x) | ((uint32_t)f2bf_rne(a.y) << 16);
    o.y = (uint32_t)f2bf_rne(a.z) | ((uint32_t)f2bf_rne(a.w) << 16);
    o.z = (uint32_t)f2bf_rne(b.x) | ((uint32_t)f2bf_rne(b.y) << 16);
    o.w = (uint32_t)f2bf_rne(b.z) | ((uint32_t)f2bf_rne(b.w) << 16);
  } else {
    o.x = o.y = o.z = o.w = 0;
  }
  *(uint4*)(x0 + e) = o;
}

// ---------- MFMA sparse conv: x[(N+1),CIN] bf16 -> y[N,64] f32 ----------
// wt: [27][64][CIN] bf16 (cout-major, cin contiguous). R row-tiles per wave.
template <int CIN, int R>
__global__ __launch_bounds__(TPB) void conv_mfma_kernel(
    const uint16_t* __restrict__ x, const uint16_t* __restrict__ wt,
    const int* __restrict__ nbr, float* __restrict__ y, int N)
{
  constexpr int CHUNKS = CIN / 32;
  constexpr int ROWB = CIN * 2;               // LDS row bytes
  constexpr int LOGROWB = (CIN == 32) ? 6 : 7;
  constexpr int SWZ = (CIN == 32) ? 3 : 7;
  constexpr int WKB = 64 * ROWB;              // per-offset W bytes
  __shared__ uint16_t Wlds[64 * CIN];

  const int tid = threadIdx.x;
  const int lane = tid & 63;
  const int wave = tid >> 6;
  const int l15 = lane & 15;
  const int l4 = lane >> 4;                   // 0..3
  const int tile0 = blockIdx.x * (4 * R) + wave * R;

  f32x4 acc[R][4];
#pragma unroll
  for (int r = 0; r < R; ++r)
#pragma unroll
    for (int t = 0; t < 4; ++t)
      acc[r][t] = (f32x4){0.f, 0.f, 0.f, 0.f};

#pragma unroll 1
  for (int k = 0; k < 27; ++k) {
    __syncthreads();
    const char* wtk = (const char*)(wt + (size_t)k * 64 * CIN);
#pragma unroll
    for (int u = 0; u < WKB / 4096; ++u) {
      int o = (tid + u * TPB) << 4;           // src byte
      int n = o >> LOGROWB;
      int b = o & (ROWB - 1);
      int d = (n << LOGROWB) | (b ^ ((n & SWZ) << 4));
      *(uint4*)((char*)Wlds + d) = *(const uint4*)(wtk + o);
    }
    __syncthreads();

    // B fragments from LDS (swizzled)
    bf16x8 bfrag[4][CHUNKS];
#pragma unroll
    for (int t = 0; t < 4; ++t) {
      int n = t * 16 + l15;
#pragma unroll
      for (int c = 0; c < CHUNKS; ++c) {
        int colb = (l4 << 4) + (c << 6);
        int d = (n << LOGROWB) | (colb ^ ((n & SWZ) << 4));
        U16x8 tmp; tmp.u = *(const uint4*)((const char*)Wlds + d);
        bfrag[t][c] = tmp.b;
      }
    }

#pragma unroll
    for (int r = 0; r < R; ++r) {
      int v = (tile0 + r) * 16 + l15;
      int g = (v < N) ? nbr[(long long)v * 27 + k] : N;  // pad row N
      const uint16_t* xr = x + (size_t)g * CIN;
#pragma unroll
      for (int c = 0; c < CHUNKS; ++c) {
        U16x8 a; a.u = *(const uint4*)(xr + c * 32 + (l4 << 3));
#pragma unroll
        for (int t = 0; t < 4; ++t)
          acc[r][t] = __builtin_amdgcn_mfma_f32_16x16x32_bf16(
              a.b, bfrag[t][c], acc[r][t], 0, 0, 0);
      }
    }
  }

  // store: C/D layout col=lane&15, row=(lane>>4)*4+reg
#pragma unroll
  for (int r = 0; r < R; ++r) {
    int vr0 = (tile0 + r) * 16 + (l4 << 2);
#pragma unroll
    for (int reg = 0; reg < 4; ++reg) {
      int vr = vr0 + reg;
      if (vr < N) {
        float* yr = y + (size_t)vr * 64 + l15;
#pragma unroll
        for (int t = 0; t < 4; ++t) yr[t * 16] = acc[r][t][reg];
      }
    }
  }
}

// ---------- per-channel sum/sumsq ----------
__global__ __launch_bounds__(TPB) void col_stats_kernel(
    const float* __restrict__ y, float* __restrict__ stats, long long N)
{
  const int c = threadIdx.x & 63;
  const int rg = threadIdx.x >> 6;
  float s = 0.f, s2 = 0.f;
  for (long long i = (long long)blockIdx.x * 4 + rg; i < N; i += (long long)gridDim.x * 4) {
    float v = y[i * 64 + c];
    s += v;
    s2 = fmaf(v, v, s2);
  }
  __shared__ float ls[2][TPB];
  ls[0][threadIdx.x] = s; ls[1][threadIdx.x] = s2;
  __syncthreads();
  if (threadIdx.x < 64) {
    float ts = ls[0][c] + ls[0][64 + c] + ls[0][128 + c] + ls[0][192 + c];
    float ts2 = ls[1][c] + ls[1][64 + c] + ls[1][128 + c] + ls[1][192 + c];
    atomicAdd(&stats[c], ts);
    atomicAdd(&stats[64 + c], ts2);
  }
}

__global__ void bn_finalize_kernel(float* stats, float n)
{
  int c = threadIdx.x;
  float mean = stats[c] / n;
  float var = stats[64 + c] / n - mean * mean;
  stats[128 + c] = mean;
  stats[192 + c] = rsqrtf(var + 1e-5f);
}

// ---------- BN + ReLU -> x1 bf16 [(N+1),64], pad row zeros ----------
__global__ __launch_bounds__(TPB) void bn_relu_bf16_kernel(
    const float* __restrict__ y, const float* __restrict__ stats,
    const float* __restrict__ gamma, const float* __restrict__ beta,
    uint16_t* __restrict__ x1, long long N)
{
  long long e = ((long long)blockIdx.x * TPB + threadIdx.x) * 4;
  if (e >= (N + 1) * 64) return;
  long long row = e >> 6;
  int c = (int)(e & 63);
  ushort4 out;
  if (row < N) {
    float4 v = *(const float4*)(y + e);
    float4 m = *(const float4*)(stats + 128 + c);
    float4 r = *(const float4*)(stats + 192 + c);
    float4 g = *(const float4*)(gamma + c);
    float4 b = *(const float4*)(beta + c);
    float o0 = fmaf((v.x - m.x) * r.x, g.x, b.x);
    float o1 = fmaf((v.y - m.y) * r.y, g.y, b.y);
    float o2 = fmaf((v.z - m.z) * r.z, g.z, b.z);
    float o3 = fmaf((v.w - m.w) * r.w, g.w, b.w);
    o0 = o0 > 0.f ? o0 : 0.f; o1 = o1 > 0.f ? o1 : 0.f;
    o2 = o2 > 0.f ? o2 : 0.f; o3 = o3 > 0.f ? o3 : 0.f;
    out.x = f2bf_rne(o0); out.y = f2bf_rne(o1); out.z = f2bf_rne(o2); out.w = f2bf_rne(o3);
  } else {
    out.x = 0; out.y = 0; out.z = 0; out.w = 0;
  }
  *(ushort4*)(x1 + e) = out;
}

// ---------- BN (no relu) -> d_out + segment-max atomics ----------
__global__ __launch_bounds__(TPB) void bn_pool_kernel(
    const float* __restrict__ y, const float* __restrict__ stats,
    const float* __restrict__ gamma, const float* __restrict__ beta,
    const int* __restrict__ pool_ids,
    float* __restrict__ xout, unsigned int* __restrict__ pooled_u, long long N)
{
  long long e = ((long long)blockIdx.x * TPB + threadIdx.x) * 4;
  if (e >= N * 64) return;
  long long row = e >> 6;
  int c = (int)(e & 63);
  float4 v = *(const float4*)(y + e);
  float4 m = *(const float4*)(stats + 128 + c);
  float4 r = *(const float4*)(stats + 192 + c);
  float4 g = *(const float4*)(gamma + c);
  float4 b = *(const float4*)(beta + c);
  float4 o;
  o.x = fmaf((v.x - m.x) * r.x, g.x, b.x);
  o.y = fmaf((v.y - m.y) * r.y, g.y, b.y);
  o.z = fmaf((v.z - m.z) * r.z, g.z, b.z);
  o.w = fmaf((v.w - m.w) * r.w, g.w, b.w);
  *(float4*)(xout + e) = o;
  int pid = pool_ids[row];
  unsigned int* pbase = pooled_u + (size_t)pid * 64 + c;
  atomicMax(pbase + 0, fkey(o.x));
  atomicMax(pbase + 1, fkey(o.y));
  atomicMax(pbase + 2, fkey(o.z));
  atomicMax(pbase + 3, fkey(o.w));
}

__global__ void pool_finalize_kernel(unsigned int* p, long long n)
{
  long long i = (long long)blockIdx.x * TPB + threadIdx.x;
  if (i < n) {
    unsigned u = p[i];
    p[i] = (u & 0x80000000u) ? (u ^ 0x80000000u) : ~u;
  }
}

extern "C" void kernel_launch(void* const* d_in, const int* in_sizes, int n_in,
                              void* d_out, int out_size, void* d_ws, size_t ws_size,
                              hipStream_t stream)
{
  const float* feats  = (const float*)d_in[0];
  const float* W1     = (const float*)d_in[1];
  const float* gamma1 = (const float*)d_in[2];
  const float* beta1  = (const float*)d_in[3];
  const float* W2     = (const float*)d_in[4];
  const float* gamma2 = (const float*)d_in[5];
  const float* beta2  = (const float*)d_in[6];
  const int* nbr      = (const int*)d_in[7];
  const int* pool_ids = (const int*)d_in[8];

  const long long N = (long long)in_sizes[0] / 32;
  const long long P = (long long)out_size / 64 - N;

  // ws: [y f32 N*64][region B: x0 bf16 (N+1)*32 then x1 bf16 (N+1)*64][stats]
  char* ws = (char*)d_ws;
  float* y = (float*)ws;
  size_t y_bytes = (size_t)N * 64 * 4;
  char* regB = ws + y_bytes;
  size_t regB_bytes = ((size_t)(N + 1) * 64 * 2 + 255) & ~(size_t)255;
  uint16_t* x0 = (uint16_t*)regB;
  uint16_t* x1 = (uint16_t*)regB;
  float* stats = (float*)(regB + regB_bytes);
  float* stats2 = stats + 256;

  float* xout = (float*)d_out;
  unsigned int* pooled_u = (unsigned int*)(xout + (size_t)N * 64);
  // bf16 W tables live in the pooled region until conv2 completes
  uint16_t* w1t = (uint16_t*)pooled_u;
  uint16_t* w2t = w1t + 27 * 2048;

  hipMemsetAsync(stats, 0, 512 * sizeof(float), stream);
  prep_w_kernel<<<(27 * 2048 + 27 * 4096 + TPB - 1) / TPB, TPB, 0, stream>>>(W1, W2, w1t, w2t);
  prep_x0_kernel<<<(int)(((N + 1) * 4 + TPB - 1) / TPB), TPB, 0, stream>>>(feats, x0, N);

  const int convBlocks = (int)((N + 255) / 256);  // 4 waves x R=4 tiles x 16 rows
  conv_mfma_kernel<32, 4><<<convBlocks, TPB, 0, stream>>>(x0, w1t, nbr, y, (int)N);
  col_stats_kernel<<<256, TPB, 0, stream>>>(y, stats, N);
  bn_finalize_kernel<<<1, 64, 0, stream>>>(stats, (float)N);

  long long e1 = ((N + 1) * 64) / 4;
  bn_relu_bf16_kernel<<<(int)((e1 + TPB - 1) / TPB), TPB, 0, stream>>>(
      y, stats, gamma1, beta1, x1, N);

  conv_mfma_kernel<64, 4><<<convBlocks, TPB, 0, stream>>>(x1, w2t, nbr, y, (int)N);
  col_stats_kernel<<<256, TPB, 0, stream>>>(y, stats2, N);
  bn_finalize_kernel<<<1, 64, 0, stream>>>(stats2, (float)N);

  hipMemsetAsync(pooled_u, 0, (size_t)P * 64 * 4, stream);
  long long e2 = (N * 64) / 4;
  bn_pool_kernel<<<(int)((e2 + TPB - 1) / TPB), TPB, 0, stream>>>(
      y, stats2, gamma2, beta2, pool_ids, xout, pooled_u, N);

  long long pe = P * 64;
  pool_finalize_kernel<<<(int)((pe + TPB - 1) / TPB), TPB, 0, stream>>>(pooled_u, pe);
}

// Round 3
// 1485.218 us; speedup vs baseline: 4.4740x; 1.8412x over previous
//
#include <hip/hip_runtime.h>
#include <hip/hip_bf16.h>
#include <stdint.h>

#define TPB 256

typedef __bf16 bf16x8 __attribute__((ext_vector_type(8)));
typedef float f32x4 __attribute__((ext_vector_type(4)));
union U16x8 { uint4 u; bf16x8 b; };

typedef const uint32_t __attribute__((address_space(1))) glb_u32;
typedef uint32_t __attribute__((address_space(3))) lds_u32;

// ---------- helpers ----------
__device__ __forceinline__ uint16_t f2bf_rne(float f) {
  union { float f; uint32_t u; } c; c.f = f;
  uint32_t r = 0x7FFFu + ((c.u >> 16) & 1u);
  return (uint16_t)((c.u + r) >> 16);
}

// ---------- prep: W -> bf16, transposed to [k][cout][cin], PRE-SWIZZLED ----------
// LDS swizzle: 16B slot s of row n holds orig slot s^(n&SWZ). Store that directly.
__global__ __launch_bounds__(TPB) void prep_w_kernel(
    const float* __restrict__ W1, const float* __restrict__ W2,
    uint16_t* __restrict__ w1t, uint16_t* __restrict__ w2t)
{
  int i = blockIdx.x * TPB + threadIdx.x;
  if (i < 27 * 2048) {
    int k = i >> 11, cin = (i >> 6) & 31, cout = i & 63;
    int cin2 = (((cin >> 3) ^ (cout & 3)) << 3) | (cin & 7);   // SWZ=3 (4 slots)
    w1t[(k << 11) + (cout << 5) + cin2] = f2bf_rne(W1[i]);
  } else {
    int j = i - 27 * 2048;
    if (j < 27 * 4096) {
      int k = j >> 12, cin = (j >> 6) & 63, cout = j & 63;
      int cin2 = (((cin >> 3) ^ (cout & 7)) << 3) | (cin & 7); // SWZ=7 (8 slots)
      w2t[(k << 12) + (cout << 6) + cin2] = f2bf_rne(W2[j]);
    }
  }
}

// ---------- prep: feats f32 [N,32] -> bf16 [(N+1),32] with zero pad row ----------
__global__ __launch_bounds__(TPB) void prep_x0_kernel(
    const float* __restrict__ feats, uint16_t* __restrict__ x0, long long N)
{
  long long t = (long long)blockIdx.x * TPB + threadIdx.x;
  if (t >= (N + 1) * 4) return;
  long long e = t * 8;
  uint4 o;
  if (e < N * 32) {
    float4 a = *(const float4*)(feats + e);
    float4 b = *(const float4*)(feats + e + 4);
    o.x = (uint32_t)f2bf_rne(a.x) | ((uint32_t)f2bf_rne(a.y) << 16);
    o.y = (uint32_t)f2bf_rne(a.z) | ((uint32_t)f2bf_rne(a.w) << 16);
    o.z = (uint32_t)f2bf_rne(b.x) | ((uint32_t)f2bf_rne(b.y) << 16);
    o.w = (uint32_t)f2bf_rne(b.z) | ((uint32_t)f2bf_rne(b.w) << 16);
  } else {
    o.x = o.y = o.z = o.w = 0;
  }
  *(uint4*)(x0 + e) = o;
}

// ---------- bucket build: pool_ids -> count[P], members[P][8] ----------
__global__ __launch_bounds__(TPB) void bucket_build_kernel(
    const int* __restrict__ pool_ids, int* __restrict__ count,
    int* __restrict__ members, long long N)
{
  long long i = (long long)blockIdx.x * TPB + threadIdx.x;
  if (i < N) {
    int pid = pool_ids[i];
    int slot = atomicAdd(&count[pid], 1);
    members[(long long)pid * 8 + slot] = (int)i;
  }
}

// ---------- MFMA sparse conv + fused column stats ----------
// x[(N+1),CIN] bf16; wt [27][64][CIN] bf16 pre-swizzled; y[N,64] f32.
// statsrep: 16 replicas x [sum[64], sumsq[64]]
template <int CIN, int R>
__global__ __launch_bounds__(TPB) void conv_mfma_kernel(
    const uint16_t* __restrict__ x, const uint16_t* __restrict__ wt,
    const int* __restrict__ nbr, float* __restrict__ y,
    float* __restrict__ statsrep, int N)
{
  constexpr int CHUNKS = CIN / 32;
  constexpr int ROWB = CIN * 2;               // LDS row bytes
  constexpr int LOGROWB = (CIN == 32) ? 6 : 7;
  constexpr int SWZ = (CIN == 32) ? 3 : 7;
  constexpr int WKB = 64 * ROWB;              // per-offset W bytes (4KB / 8KB)
  constexpr int NISSUE = WKB / (TPB * 16);
  __shared__ __align__(16) char Wlds[2][WKB];
  __shared__ float sred[4][128];

  const int tid = threadIdx.x;
  const int lane = tid & 63;
  const int wave = tid >> 6;
  const int l15 = lane & 15;
  const int l4 = lane >> 4;                   // 0..3
  const int tile0 = blockIdx.x * (4 * R) + wave * R;

  f32x4 acc[R][4];
#pragma unroll
  for (int r = 0; r < R; ++r)
#pragma unroll
    for (int t = 0; t < 4; ++t)
      acc[r][t] = (f32x4){0.f, 0.f, 0.f, 0.f};

  // prologue: stage k=0 (linear dest, pre-swizzled source)
  {
    const char* src = (const char*)wt;
#pragma unroll
    for (int u = 0; u < NISSUE; ++u) {
      int off = (tid + u * TPB) * 16;
      __builtin_amdgcn_global_load_lds((glb_u32*)(src + off),
                                       (lds_u32*)(&Wlds[0][off]), 16, 0, 0);
    }
  }

#pragma unroll 1
  for (int k = 0; k < 27; ++k) {
    const int cur = k & 1;
    __syncthreads();  // drains vmcnt: buf[cur] ready; everyone done reading buf[cur^1]
    if (k + 1 < 27) {
      const char* src = (const char*)(wt + (size_t)(k + 1) * 64 * CIN);
#pragma unroll
      for (int u = 0; u < NISSUE; ++u) {
        int off = (tid + u * TPB) * 16;
        __builtin_amdgcn_global_load_lds((glb_u32*)(src + off),
                                         (lds_u32*)(&Wlds[cur ^ 1][off]), 16, 0, 0);
      }
    }

    // B fragments from LDS (swizzled read)
    bf16x8 bfrag[4][CHUNKS];
#pragma unroll
    for (int t = 0; t < 4; ++t) {
      int n = t * 16 + l15;
#pragma unroll
      for (int c = 0; c < CHUNKS; ++c) {
        int colb = (l4 << 4) + (c << 6);
        int d = (n << LOGROWB) | (colb ^ ((n & SWZ) << 4));
        U16x8 tmp; tmp.u = *(const uint4*)(&Wlds[cur][d]);
        bfrag[t][c] = tmp.b;
      }
    }

#pragma unroll
    for (int r = 0; r < R; ++r) {
      int v = (tile0 + r) * 16 + l15;
      int g = (v < N) ? nbr[(long long)v * 27 + k] : N;  // pad row N (zeros)
      const uint16_t* xr = x + (size_t)g * CIN;
#pragma unroll
      for (int c = 0; c < CHUNKS; ++c) {
        U16x8 a; a.u = *(const uint4*)(xr + c * 32 + (l4 << 3));
#pragma unroll
        for (int t = 0; t < 4; ++t)
          acc[r][t] = __builtin_amdgcn_mfma_f32_16x16x32_bf16(
              a.b, bfrag[t][c], acc[r][t], 0, 0, 0);
      }
    }
  }

  // ---- store y: C/D layout col=lane&15, row=(lane>>4)*4+reg ----
#pragma unroll
  for (int r = 0; r < R; ++r) {
    int vr0 = (tile0 + r) * 16 + (l4 << 2);
#pragma unroll
    for (int reg = 0; reg < 4; ++reg) {
      int vr = vr0 + reg;
      if (vr < N) {
        float* yr = y + (size_t)vr * 64 + l15;
#pragma unroll
        for (int t = 0; t < 4; ++t) yr[t * 16] = acc[r][t][reg];
      }
    }
  }

  // ---- fused column stats: per-thread sums over valid rows ----
  float s[4], s2[4];
#pragma unroll
  for (int t = 0; t < 4; ++t) { s[t] = 0.f; s2[t] = 0.f; }
#pragma unroll
  for (int r = 0; r < R; ++r) {
    int vr0 = (tile0 + r) * 16 + (l4 << 2);
#pragma unroll
    for (int reg = 0; reg < 4; ++reg) {
      if (vr0 + reg < N) {
#pragma unroll
        for (int t = 0; t < 4; ++t) {
          float v = acc[r][t][reg];
          s[t] += v;
          s2[t] = fmaf(v, v, s2[t]);
        }
      }
    }
  }
  // reduce over the 4 lanes sharing a column (l4 axis): xor 16, 32
#pragma unroll
  for (int t = 0; t < 4; ++t) {
    s[t] += __shfl_xor(s[t], 16);
    s[t] += __shfl_xor(s[t], 32);
    s2[t] += __shfl_xor(s2[t], 16);
    s2[t] += __shfl_xor(s2[t], 32);
  }
  __syncthreads();  // Wlds reads done; reuse barrier before sred writes
  if (l4 == 0) {
#pragma unroll
    for (int t = 0; t < 4; ++t) {
      sred[wave][t * 16 + l15] = s[t];
      sred[wave][64 + t * 16 + l15] = s2[t];
    }
  }
  __syncthreads();
  if (tid < 128) {
    float tot = sred[0][tid] + sred[1][tid] + sred[2][tid] + sred[3][tid];
    atomicAdd(&statsrep[(blockIdx.x & 15) * 128 + tid], tot);
  }
}

// ---------- finalize: 16 replicas -> fin[0..63]=mean, fin[64..127]=rstd ----------
__global__ void bn_finalize_kernel(const float* __restrict__ reps,
                                   float* __restrict__ fin, float n)
{
  int c = threadIdx.x; // 64 threads
  float s = 0.f, s2 = 0.f;
  for (int r = 0; r < 16; ++r) { s += reps[r * 128 + c]; s2 += reps[r * 128 + 64 + c]; }
  float mean = s / n;
  float var = s2 / n - mean * mean;
  fin[c] = mean;
  fin[64 + c] = rsqrtf(var + 1e-5f);
}

// ---------- BN + ReLU -> x1 bf16 [(N+1),64], pad row zeros ----------
__global__ __launch_bounds__(TPB) void bn_relu_bf16_kernel(
    const float* __restrict__ y, const float* __restrict__ fin,
    const float* __restrict__ gamma, const float* __restrict__ beta,
    uint16_t* __restrict__ x1, long long N)
{
  long long e = ((long long)blockIdx.x * TPB + threadIdx.x) * 4;
  if (e >= (N + 1) * 64) return;
  long long row = e >> 6;
  int c = (int)(e & 63);
  ushort4 out;
  if (row < N) {
    float4 v = *(const float4*)(y + e);
    float4 m = *(const float4*)(fin + c);
    float4 r = *(const float4*)(fin + 64 + c);
    float4 g = *(const float4*)(gamma + c);
    float4 b = *(const float4*)(beta + c);
    float o0 = fmaf((v.x - m.x) * r.x, g.x, b.x);
    float o1 = fmaf((v.y - m.y) * r.y, g.y, b.y);
    float o2 = fmaf((v.z - m.z) * r.z, g.z, b.z);
    float o3 = fmaf((v.w - m.w) * r.w, g.w, b.w);
    o0 = o0 > 0.f ? o0 : 0.f; o1 = o1 > 0.f ? o1 : 0.f;
    o2 = o2 > 0.f ? o2 : 0.f; o3 = o3 > 0.f ? o3 : 0.f;
    out.x = f2bf_rne(o0); out.y = f2bf_rne(o1); out.z = f2bf_rne(o2); out.w = f2bf_rne(o3);
  } else {
    out.x = 0; out.y = 0; out.z = 0; out.w = 0;
  }
  *(ushort4*)(x1 + e) = out;
}

// ---------- segment max: per segment, gather members from y, BN, write pooled ----------
__global__ __launch_bounds__(TPB) void pool_max_kernel(
    const float* __restrict__ y, const float* __restrict__ fin,
    const float* __restrict__ gamma, const float* __restrict__ beta,
    const int* __restrict__ count, const int* __restrict__ members,
    float* __restrict__ pooled, long long P)
{
  long long pid = (long long)blockIdx.x * 16 + (threadIdx.x >> 4);
  if (pid >= P) return;
  int c0 = (threadIdx.x & 15) * 4;
  float4 m = *(const float4*)(fin + c0);
  float4 r = *(const float4*)(fin + 64 + c0);
  float4 g = *(const float4*)(gamma + c0);
  float4 b = *(const float4*)(beta + c0);
  int cnt = count[pid];
  float4 acc = {-3.4e38f, -3.4e38f, -3.4e38f, -3.4e38f};
  const int* mem = members + pid * 8;
  for (int t = 0; t < cnt; ++t) {
    long long row = mem[t];
    float4 v = *(const float4*)(y + row * 64 + c0);
    acc.x = fmaxf(acc.x, fmaf((v.x - m.x) * r.x, g.x, b.x));
    acc.y = fmaxf(acc.y, fmaf((v.y - m.y) * r.y, g.y, b.y));
    acc.z = fmaxf(acc.z, fmaf((v.z - m.z) * r.z, g.z, b.z));
    acc.w = fmaxf(acc.w, fmaf((v.w - m.w) * r.w, g.w, b.w));
  }
  *(float4*)(pooled + pid * 64 + c0) = acc;
}

// ---------- BN (no relu) -> xout ----------
__global__ __launch_bounds__(TPB) void bn_write_kernel(
    const float* __restrict__ y, const float* __restrict__ fin,
    const float* __restrict__ gamma, const float* __restrict__ beta,
    float* __restrict__ xout, long long N)
{
  long long e = ((long long)blockIdx.x * TPB + threadIdx.x) * 4;
  if (e >= N * 64) return;
  int c = (int)(e & 63);
  float4 v = *(const float4*)(y + e);
  float4 m = *(const float4*)(fin + c);
  float4 r = *(const float4*)(fin + 64 + c);
  float4 g = *(const float4*)(gamma + c);
  float4 b = *(const float4*)(beta + c);
  float4 o;
  o.x = fmaf((v.x - m.x) * r.x, g.x, b.x);
  o.y = fmaf((v.y - m.y) * r.y, g.y, b.y);
  o.z = fmaf((v.z - m.z) * r.z, g.z, b.z);
  o.w = fmaf((v.w - m.w) * r.w, g.w, b.w);
  *(float4*)(xout + e) = o;
}

extern "C" void kernel_launch(void* const* d_in, const int* in_sizes, int n_in,
                              void* d_out, int out_size, void* d_ws, size_t ws_size,
                              hipStream_t stream)
{
  const float* feats  = (const float*)d_in[0];
  const float* W1     = (const float*)d_in[1];
  const float* gamma1 = (const float*)d_in[2];
  const float* beta1  = (const float*)d_in[3];
  const float* W2     = (const float*)d_in[4];
  const float* gamma2 = (const float*)d_in[5];
  const float* beta2  = (const float*)d_in[6];
  const int* nbr      = (const int*)d_in[7];
  const int* pool_ids = (const int*)d_in[8];

  const long long N = (long long)in_sizes[0] / 32;
  const long long P = (long long)out_size / 64 - N;

  // ws: [y f32 N*64][x1 bf16 (N+1)*64][statsrep 2x16x128 f32][fin 2x128 f32]
  char* ws = (char*)d_ws;
  float* y = (float*)ws;
  size_t y_bytes = (size_t)N * 64 * 4;
  char* regB = ws + y_bytes;
  size_t regB_bytes = ((size_t)(N + 1) * 64 * 2 + 255) & ~(size_t)255;
  uint16_t* x0 = (uint16_t*)regB;   // [(N+1),32] for conv1
  uint16_t* x1 = (uint16_t*)regB;   // [(N+1),64] for conv2 (reuses region)
  float* reps1 = (float*)(regB + regB_bytes);   // 16*128
  float* reps2 = reps1 + 16 * 128;
  float* fin1 = reps2 + 16 * 128;               // 128
  float* fin2 = fin1 + 128;

  float* xout = (float*)d_out;
  float* pooled = xout + (size_t)N * 64;
  // temp aliases (dead before their regions are overwritten):
  int* count   = (int*)xout;                    // [P] ints, in xout region
  int* members = count + P;                     // [P*8] ints
  uint16_t* w1t = (uint16_t*)pooled;            // bf16 W tables in pooled region
  uint16_t* w2t = w1t + 27 * 2048;

  hipMemsetAsync(reps1, 0, 2 * 16 * 128 * sizeof(float), stream);
  hipMemsetAsync(count, 0, (size_t)P * 4, stream);

  prep_w_kernel<<<(27 * 2048 + 27 * 4096 + TPB - 1) / TPB, TPB, 0, stream>>>(W1, W2, w1t, w2t);
  prep_x0_kernel<<<(int)(((N + 1) * 4 + TPB - 1) / TPB), TPB, 0, stream>>>(feats, x0, N);
  bucket_build_kernel<<<(int)((N + TPB - 1) / TPB), TPB, 0, stream>>>(pool_ids, count, members, N);

  const int convBlocks = (int)((N + 255) / 256);  // 4 waves x R=4 x 16 rows
  conv_mfma_kernel<32, 4><<<convBlocks, TPB, 0, stream>>>(x0, w1t, nbr, y, reps1, (int)N);
  bn_finalize_kernel<<<1, 64, 0, stream>>>(reps1, fin1, (float)N);

  long long e1 = ((N + 1) * 64) / 4;
  bn_relu_bf16_kernel<<<(int)((e1 + TPB - 1) / TPB), TPB, 0, stream>>>(
      y, fin1, gamma1, beta1, x1, N);

  conv_mfma_kernel<64, 4><<<convBlocks, TPB, 0, stream>>>(x1, w2t, nbr, y, reps2, (int)N);
  bn_finalize_kernel<<<1, 64, 0, stream>>>(reps2, fin2, (float)N);

  // pool_max BEFORE bn_write: buckets live in xout region until consumed
  pool_max_kernel<<<(int)((P + 15) / 16), TPB, 0, stream>>>(
      y, fin2, gamma2, beta2, count, members, pooled, P);

  long long e2 = (N * 64) / 4;
  bn_write_kernel<<<(int)((e2 + TPB - 1) / TPB), TPB, 0, stream>>>(
      y, fin2, gamma2, beta2, xout, N);
}

// Round 4
// 758.857 us; speedup vs baseline: 8.7565x; 1.9572x over previous
//
#include <hip/hip_runtime.h>
#include <hip/hip_bf16.h>
#include <stdint.h>

#define TPB 256

typedef __bf16 bf16x8 __attribute__((ext_vector_type(8)));
typedef float f32x4 __attribute__((ext_vector_type(4)));
union U16x8 { uint4 u; bf16x8 b; };

typedef const uint32_t __attribute__((address_space(1))) glb_u32;
typedef uint32_t __attribute__((address_space(3))) lds_u32;

// ---------- helpers ----------
__device__ __forceinline__ uint16_t f2bf_rne(float f) {
  union { float f; uint32_t u; } c; c.f = f;
  uint32_t r = 0x7FFFu + ((c.u >> 16) & 1u);
  return (uint16_t)((c.u + r) >> 16);
}

// ---------- prep: W -> bf16, transposed to [k][cout][cin], PRE-SWIZZLED ----------
__global__ __launch_bounds__(TPB) void prep_w_kernel(
    const float* __restrict__ W1, const float* __restrict__ W2,
    uint16_t* __restrict__ w1t, uint16_t* __restrict__ w2t)
{
  int i = blockIdx.x * TPB + threadIdx.x;
  if (i < 27 * 2048) {
    int k = i >> 11, cin = (i >> 6) & 31, cout = i & 63;
    int cin2 = (((cin >> 3) ^ (cout & 3)) << 3) | (cin & 7);   // SWZ=3
    w1t[(k << 11) + (cout << 5) + cin2] = f2bf_rne(W1[i]);
  } else {
    int j = i - 27 * 2048;
    if (j < 27 * 4096) {
      int k = j >> 12, cin = (j >> 6) & 63, cout = j & 63;
      int cin2 = (((cin >> 3) ^ (cout & 7)) << 3) | (cin & 7); // SWZ=7
      w2t[(k << 12) + (cout << 6) + cin2] = f2bf_rne(W2[j]);
    }
  }
}

// ---------- prep: feats f32 [N,32] -> bf16 [(N+1),32] with zero pad row ----------
__global__ __launch_bounds__(TPB) void prep_x0_kernel(
    const float* __restrict__ feats, uint16_t* __restrict__ x0, long long N)
{
  long long t = (long long)blockIdx.x * TPB + threadIdx.x;
  if (t >= (N + 1) * 4) return;
  long long e = t * 8;
  uint4 o;
  if (e < N * 32) {
    float4 a = *(const float4*)(feats + e);
    float4 b = *(const float4*)(feats + e + 4);
    o.x = (uint32_t)f2bf_rne(a.x) | ((uint32_t)f2bf_rne(a.y) << 16);
    o.y = (uint32_t)f2bf_rne(a.z) | ((uint32_t)f2bf_rne(a.w) << 16);
    o.z = (uint32_t)f2bf_rne(b.x) | ((uint32_t)f2bf_rne(b.y) << 16);
    o.w = (uint32_t)f2bf_rne(b.z) | ((uint32_t)f2bf_rne(b.w) << 16);
  } else {
    o.x = o.y = o.z = o.w = 0;
  }
  *(uint4*)(x0 + e) = o;
}

// ---------- bucket build ----------
__global__ __launch_bounds__(TPB) void bucket_build_kernel(
    const int* __restrict__ pool_ids, int* __restrict__ count,
    int* __restrict__ members, long long N)
{
  long long i = (long long)blockIdx.x * TPB + threadIdx.x;
  if (i < N) {
    int pid = pool_ids[i];
    int slot = atomicAdd(&count[pid], 1);
    members[(long long)pid * 8 + slot] = (int)i;
  }
}

// ---------- MFMA sparse conv, pipelined gathers + fused column stats ----------
template <int CIN, int R>
__global__ __launch_bounds__(TPB, 2) void conv_mfma_kernel(
    const uint16_t* __restrict__ x, const uint16_t* __restrict__ wt,
    const int* __restrict__ nbr, float* __restrict__ y,
    float* __restrict__ statsrep, int N)
{
  constexpr int CHUNKS = CIN / 32;
  constexpr int LOGROWB = (CIN == 32) ? 6 : 7;
  constexpr int SWZ = (CIN == 32) ? 3 : 7;
  constexpr int WKB = 64 * CIN * 2;           // per-offset W bytes
  constexpr int NISSUE = WKB / (TPB * 16);
  constexpr int ROWS = 4 * R * 16;            // rows per block = 256
  constexpr int NINTS = ROWS * 27;            // 6912
  constexpr int NCH16 = NINTS / 4;            // 1728 uint4 chunks

  __shared__ __align__(16) char Wlds[2][WKB];
  __shared__ __align__(16) int nbrLds[NINTS]; // 27 KB
  __shared__ float sred[4][128];

  const int tid = threadIdx.x;
  const int lane = tid & 63;
  const int wave = tid >> 6;
  const int l15 = lane & 15;
  const int l4 = lane >> 4;
  const long long row0 = (long long)blockIdx.x * ROWS;

  f32x4 acc[R][4];
#pragma unroll
  for (int r = 0; r < R; ++r)
#pragma unroll
    for (int t = 0; t < 4; ++t)
      acc[r][t] = (f32x4){0.f, 0.f, 0.f, 0.f};

  // ---- stage nbr tile (coalesced DMA + scalar tail) ----
  {
    const char* nsrc = (const char*)nbr + row0 * 108;       // 27*4 B per row
    long long blkB = (long long)N * 108 - row0 * 108;       // bytes available
    int fullChunks = (int)(blkB >> 4);
    if (fullChunks > NCH16) fullChunks = NCH16;
#pragma unroll
    for (int u = 0; u < (NCH16 + TPB - 1) / TPB; ++u) {
      int idx = u * TPB + tid;
      if (idx < fullChunks)
        __builtin_amdgcn_global_load_lds((glb_u32*)(nsrc + idx * 16),
                                         (lds_u32*)((char*)nbrLds + idx * 16), 16, 0, 0);
    }
    for (int ii = fullChunks * 4 + tid; ii < NINTS; ii += TPB) {
      long long gi = row0 * 27 + ii;
      nbrLds[ii] = (gi < (long long)N * 27) ? nbr[gi] : N;
    }
  }

  auto stageW = [&](int k, int b) {
    const char* src = (const char*)(wt + (size_t)k * 64 * CIN);
#pragma unroll
    for (int u = 0; u < NISSUE; ++u) {
      int off = (tid + u * TPB) * 16;
      __builtin_amdgcn_global_load_lds((glb_u32*)(src + off),
                                       (lds_u32*)(&Wlds[b][off]), 16, 0, 0);
    }
  };
  auto gather = [&](int k, U16x8 (&dst)[R][CHUNKS]) {
#pragma unroll
    for (int r = 0; r < R; ++r) {
      int lrow = (wave * R + r) * 16 + l15;
      int g = nbrLds[lrow * 27 + k];
      const uint16_t* xr = x + (size_t)g * CIN + (l4 << 3);
#pragma unroll
      for (int c = 0; c < CHUNKS; ++c)
        dst[r][c].u = *(const uint4*)(xr + c * 32);
    }
  };
  auto compute = [&](int wsel, U16x8 (&xs)[R][CHUNKS]) {
    bf16x8 bfrag[4][CHUNKS];
#pragma unroll
    for (int t = 0; t < 4; ++t) {
      int n = t * 16 + l15;
#pragma unroll
      for (int c = 0; c < CHUNKS; ++c) {
        int colb = (l4 << 4) + (c << 6);
        int d = (n << LOGROWB) | (colb ^ ((n & SWZ) << 4));
        U16x8 tmp; tmp.u = *(const uint4*)(&Wlds[wsel][d]);
        bfrag[t][c] = tmp.b;
      }
    }
#pragma unroll
    for (int r = 0; r < R; ++r)
#pragma unroll
      for (int c = 0; c < CHUNKS; ++c)
#pragma unroll
        for (int t = 0; t < 4; ++t)
          acc[r][t] = __builtin_amdgcn_mfma_f32_16x16x32_bf16(
              xs[r][c].b, bfrag[t][c], acc[r][t], 0, 0, 0);
  };

  U16x8 xA[R][CHUNKS], xB[R][CHUNKS];

  stageW(0, 0);
  __syncthreads();           // nbr tile + W0 ready
  gather(0, xA);

#pragma unroll 1
  for (int kk = 0; kk < 13; ++kk) {
    if (kk > 0) __syncthreads();    // W[buf0] (k=2kk) staged; buf1 free
    stageW(2 * kk + 1, 1);
    gather(2 * kk + 1, xB);
    compute(0, xA);                 // k = 2kk (even -> buf0)
    __syncthreads();                // W[buf1] ready; buf0 free
    if (2 * kk + 2 < 27) {
      stageW(2 * kk + 2, 0);
      gather(2 * kk + 2, xA);
    }
    compute(1, xB);                 // k = 2kk+1 (odd -> buf1)
  }
  __syncthreads();                  // W[buf0] (k=26) ready
  compute(0, xA);                   // k = 26

  // ---- store y: C/D layout col=lane&15, row=(lane>>4)*4+reg ----
#pragma unroll
  for (int r = 0; r < R; ++r) {
    long long vr0 = row0 + (wave * R + r) * 16 + (l4 << 2);
#pragma unroll
    for (int reg = 0; reg < 4; ++reg) {
      long long vr = vr0 + reg;
      if (vr < N) {
        float* yr = y + vr * 64 + l15;
#pragma unroll
        for (int t = 0; t < 4; ++t) yr[t * 16] = acc[r][t][reg];
      }
    }
  }

  // ---- fused column stats ----
  float s[4], s2[4];
#pragma unroll
  for (int t = 0; t < 4; ++t) { s[t] = 0.f; s2[t] = 0.f; }
#pragma unroll
  for (int r = 0; r < R; ++r) {
    long long vr0 = row0 + (wave * R + r) * 16 + (l4 << 2);
#pragma unroll
    for (int reg = 0; reg < 4; ++reg) {
      if (vr0 + reg < N) {
#pragma unroll
        for (int t = 0; t < 4; ++t) {
          float v = acc[r][t][reg];
          s[t] += v;
          s2[t] = fmaf(v, v, s2[t]);
        }
      }
    }
  }
#pragma unroll
  for (int t = 0; t < 4; ++t) {
    s[t] += __shfl_xor(s[t], 16);
    s[t] += __shfl_xor(s[t], 32);
    s2[t] += __shfl_xor(s2[t], 16);
    s2[t] += __shfl_xor(s2[t], 32);
  }
  __syncthreads();
  if (l4 == 0) {
#pragma unroll
    for (int t = 0; t < 4; ++t) {
      sred[wave][t * 16 + l15] = s[t];
      sred[wave][64 + t * 16 + l15] = s2[t];
    }
  }
  __syncthreads();
  if (tid < 128) {
    float tot = sred[0][tid] + sred[1][tid] + sred[2][tid] + sred[3][tid];
    atomicAdd(&statsrep[(blockIdx.x & 15) * 128 + tid], tot);
  }
}

// ---------- finalize ----------
__global__ void bn_finalize_kernel(const float* __restrict__ reps,
                                   float* __restrict__ fin, float n)
{
  int c = threadIdx.x;
  float s = 0.f, s2 = 0.f;
  for (int r = 0; r < 16; ++r) { s += reps[r * 128 + c]; s2 += reps[r * 128 + 64 + c]; }
  float mean = s / n;
  float var = s2 / n - mean * mean;
  fin[c] = mean;
  fin[64 + c] = rsqrtf(var + 1e-5f);
}

// ---------- BN + ReLU -> x1 bf16 [(N+1),64], pad row zeros ----------
__global__ __launch_bounds__(TPB) void bn_relu_bf16_kernel(
    const float* __restrict__ y, const float* __restrict__ fin,
    const float* __restrict__ gamma, const float* __restrict__ beta,
    uint16_t* __restrict__ x1, long long N)
{
  long long e = ((long long)blockIdx.x * TPB + threadIdx.x) * 4;
  if (e >= (N + 1) * 64) return;
  long long row = e >> 6;
  int c = (int)(e & 63);
  ushort4 out;
  if (row < N) {
    float4 v = *(const float4*)(y + e);
    float4 m = *(const float4*)(fin + c);
    float4 r = *(const float4*)(fin + 64 + c);
    float4 g = *(const float4*)(gamma + c);
    float4 b = *(const float4*)(beta + c);
    float o0 = fmaf((v.x - m.x) * r.x, g.x, b.x);
    float o1 = fmaf((v.y - m.y) * r.y, g.y, b.y);
    float o2 = fmaf((v.z - m.z) * r.z, g.z, b.z);
    float o3 = fmaf((v.w - m.w) * r.w, g.w, b.w);
    o0 = o0 > 0.f ? o0 : 0.f; o1 = o1 > 0.f ? o1 : 0.f;
    o2 = o2 > 0.f ? o2 : 0.f; o3 = o3 > 0.f ? o3 : 0.f;
    out.x = f2bf_rne(o0); out.y = f2bf_rne(o1); out.z = f2bf_rne(o2); out.w = f2bf_rne(o3);
  } else {
    out.x = 0; out.y = 0; out.z = 0; out.w = 0;
  }
  *(ushort4*)(x1 + e) = out;
}

// ---------- segment max via buckets ----------
__global__ __launch_bounds__(TPB) void pool_max_kernel(
    const float* __restrict__ y, const float* __restrict__ fin,
    const float* __restrict__ gamma, const float* __restrict__ beta,
    const int* __restrict__ count, const int* __restrict__ members,
    float* __restrict__ pooled, long long P)
{
  long long pid = (long long)blockIdx.x * 16 + (threadIdx.x >> 4);
  if (pid >= P) return;
  int c0 = (threadIdx.x & 15) * 4;
  float4 m = *(const float4*)(fin + c0);
  float4 r = *(const float4*)(fin + 64 + c0);
  float4 g = *(const float4*)(gamma + c0);
  float4 b = *(const float4*)(beta + c0);
  int cnt = count[pid];
  float4 acc = {-3.4e38f, -3.4e38f, -3.4e38f, -3.4e38f};
  const int* mem = members + pid * 8;
  for (int t = 0; t < cnt; ++t) {
    long long row = mem[t];
    float4 v = *(const float4*)(y + row * 64 + c0);
    acc.x = fmaxf(acc.x, fmaf((v.x - m.x) * r.x, g.x, b.x));
    acc.y = fmaxf(acc.y, fmaf((v.y - m.y) * r.y, g.y, b.y));
    acc.z = fmaxf(acc.z, fmaf((v.z - m.z) * r.z, g.z, b.z));
    acc.w = fmaxf(acc.w, fmaf((v.w - m.w) * r.w, g.w, b.w));
  }
  *(float4*)(pooled + pid * 64 + c0) = acc;
}

// ---------- BN (no relu) -> xout ----------
__global__ __launch_bounds__(TPB) void bn_write_kernel(
    const float* __restrict__ y, const float* __restrict__ fin,
    const float* __restrict__ gamma, const float* __restrict__ beta,
    float* __restrict__ xout, long long N)
{
  long long e = ((long long)blockIdx.x * TPB + threadIdx.x) * 4;
  if (e >= N * 64) return;
  int c = (int)(e & 63);
  float4 v = *(const float4*)(y + e);
  float4 m = *(const float4*)(fin + c);
  float4 r = *(const float4*)(fin + 64 + c);
  float4 g = *(const float4*)(gamma + c);
  float4 b = *(const float4*)(beta + c);
  float4 o;
  o.x = fmaf((v.x - m.x) * r.x, g.x, b.x);
  o.y = fmaf((v.y - m.y) * r.y, g.y, b.y);
  o.z = fmaf((v.z - m.z) * r.z, g.z, b.z);
  o.w = fmaf((v.w - m.w) * r.w, g.w, b.w);
  *(float4*)(xout + e) = o;
}

extern "C" void kernel_launch(void* const* d_in, const int* in_sizes, int n_in,
                              void* d_out, int out_size, void* d_ws, size_t ws_size,
                              hipStream_t stream)
{
  const float* feats  = (const float*)d_in[0];
  const float* W1     = (const float*)d_in[1];
  const float* gamma1 = (const float*)d_in[2];
  const float* beta1  = (const float*)d_in[3];
  const float* W2     = (const float*)d_in[4];
  const float* gamma2 = (const float*)d_in[5];
  const float* beta2  = (const float*)d_in[6];
  const int* nbr      = (const int*)d_in[7];
  const int* pool_ids = (const int*)d_in[8];

  const long long N = (long long)in_sizes[0] / 32;
  const long long P = (long long)out_size / 64 - N;

  char* ws = (char*)d_ws;
  float* y = (float*)ws;
  size_t y_bytes = (size_t)N * 64 * 4;
  char* regB = ws + y_bytes;
  size_t regB_bytes = ((size_t)(N + 1) * 64 * 2 + 255) & ~(size_t)255;
  uint16_t* x0 = (uint16_t*)regB;
  uint16_t* x1 = (uint16_t*)regB;
  float* reps1 = (float*)(regB + regB_bytes);
  float* reps2 = reps1 + 16 * 128;
  float* fin1 = reps2 + 16 * 128;
  float* fin2 = fin1 + 128;

  float* xout = (float*)d_out;
  float* pooled = xout + (size_t)N * 64;
  int* count   = (int*)xout;
  int* members = count + P;
  uint16_t* w1t = (uint16_t*)pooled;
  uint16_t* w2t = w1t + 27 * 2048;

  hipMemsetAsync(reps1, 0, 2 * 16 * 128 * sizeof(float), stream);
  hipMemsetAsync(count, 0, (size_t)P * 4, stream);

  prep_w_kernel<<<(27 * 2048 + 27 * 4096 + TPB - 1) / TPB, TPB, 0, stream>>>(W1, W2, w1t, w2t);
  prep_x0_kernel<<<(int)(((N + 1) * 4 + TPB - 1) / TPB), TPB, 0, stream>>>(feats, x0, N);
  bucket_build_kernel<<<(int)((N + TPB - 1) / TPB), TPB, 0, stream>>>(pool_ids, count, members, N);

  const int convBlocks = (int)((N + 255) / 256);
  conv_mfma_kernel<32, 4><<<convBlocks, TPB, 0, stream>>>(x0, w1t, nbr, y, reps1, (int)N);
  bn_finalize_kernel<<<1, 64, 0, stream>>>(reps1, fin1, (float)N);

  long long e1 = ((N + 1) * 64) / 4;
  bn_relu_bf16_kernel<<<(int)((e1 + TPB - 1) / TPB), TPB, 0, stream>>>(
      y, fin1, gamma1, beta1, x1, N);

  conv_mfma_kernel<64, 4><<<convBlocks, TPB, 0, stream>>>(x1, w2t, nbr, y, reps2, (int)N);
  bn_finalize_kernel<<<1, 64, 0, stream>>>(reps2, fin2, (float)N);

  pool_max_kernel<<<(int)((P + 15) / 16), TPB, 0, stream>>>(
      y, fin2, gamma2, beta2, count, members, pooled, P);

  long long e2 = (N * 64) / 4;
  bn_write_kernel<<<(int)((e2 + TPB - 1) / TPB), TPB, 0, stream>>>(
      y, fin2, gamma2, beta2, xout, N);
}